// Round 4
// baseline (1620.394 us; speedup 1.0000x reference)
//
#include <hip/hip_runtime.h>
#include <stdint.h>
#include <stddef.h>

#define HID 2048
#define NB 128
#define NG 8192
#define ODIM 63

// ---------------- threefry2x32 core (JAX-exact) ----------------
__device__ __forceinline__ void tf2x32(uint32_t k0, uint32_t k1,
                                       uint32_t x0, uint32_t x1,
                                       uint32_t& o0, uint32_t& o1) {
  uint32_t ks2 = k0 ^ k1 ^ 0x1BD11BDAu;
  x0 += k0; x1 += k1;
#define TF_ROTL(v,d) (((v)<<(d))|((v)>>(32-(d))))
#define TF_R(r) { x0 += x1; x1 = TF_ROTL(x1,r); x1 ^= x0; }
  TF_R(13) TF_R(15) TF_R(26) TF_R(6)
  x0 += k1;  x1 += ks2 + 1u;
  TF_R(17) TF_R(29) TF_R(16) TF_R(24)
  x0 += ks2; x1 += k0 + 2u;
  TF_R(13) TF_R(15) TF_R(26) TF_R(6)
  x0 += k0;  x1 += k1 + 3u;
  TF_R(17) TF_R(29) TF_R(16) TF_R(24)
  x0 += k1;  x1 += ks2 + 4u;
  TF_R(13) TF_R(15) TF_R(26) TF_R(6)
  x0 += ks2; x1 += k0 + 5u;
  o0 = x0; o1 = x1;
#undef TF_R
#undef TF_ROTL
}

__device__ __forceinline__ float unif01(uint32_t b) {
  return __uint_as_float((b >> 9) | 0x3f800000u) - 1.0f;
}

// XLA ErfInv (Giles polynomial, f32)
__device__ __forceinline__ float erfinv_xla(float x) {
  float t = x * x;
  float w = -log1pf(-t);
  float p;
  if (w < 5.0f) {
    w = w - 2.5f;
    p = 2.81022636e-08f;
    p = fmaf(p, w, 3.43273939e-07f);
    p = fmaf(p, w, -3.5233877e-06f);
    p = fmaf(p, w, -4.39150654e-06f);
    p = fmaf(p, w, 0.00021858087f);
    p = fmaf(p, w, -0.00125372503f);
    p = fmaf(p, w, -0.00417768164f);
    p = fmaf(p, w, 0.246640727f);
    p = fmaf(p, w, 1.50140941f);
  } else {
    w = sqrtf(w) - 3.0f;
    p = -0.000200214257f;
    p = fmaf(p, w, 0.000100950558f);
    p = fmaf(p, w, 0.00134934322f);
    p = fmaf(p, w, -0.00367342844f);
    p = fmaf(p, w, 0.00573950773f);
    p = fmaf(p, w, -0.0076224613f);
    p = fmaf(p, w, 0.00943887047f);
    p = fmaf(p, w, 1.00167406f);
    p = fmaf(p, w, 2.83297682f);
  }
  return p * x;
}

__device__ __forceinline__ float norm_from_bits(uint32_t b) {
  float f = unif01(b);
  // u = f * (hi - lo) + lo ; hi - lo = 1 - nextafter(-1,0) rounds to exactly 2.0f
  float v = f * 2.0f + __uint_as_float(0xBF7FFFFFu);
  return __uint_as_float(0x3FB504F3u) * erfinv_xla(v); // sqrt(2) f32
}

// Per-step randomness, PARTITIONABLE threefry scheme (JAX >= 0.4.36 default):
//   split(key, n):      key_i = (o0, o1) of threefry(key, counter=(0, i))
//   random_bits 32-bit: bits[l] = o0 ^ o1 of threefry(key, counter=(0, l))
__global__ void rand_kernel(float* __restrict__ u, float* __restrict__ rx,
                            float* __restrict__ ry, float* __restrict__ u2,
                            float* __restrict__ stroke) {
  const int i = blockIdx.x;   // step 0..9
  const int l = threadIdx.x;  // batch element 0..127
  if (i == 0) {
    stroke[l*5+0] = 0.f; stroke[l*5+1] = 0.f; stroke[l*5+2] = 1.f;
    stroke[l*5+3] = 0.f; stroke[l*5+4] = 0.f;
  }
  // keys = split(key(42), 10): keys[i] = tf((0,42), (0, i)), both outputs
  uint32_t ki0, ki1;
  tf2x32(0u, 42u, 0u, (uint32_t)i, ki0, ki1);
  // k1..k4 = split(keys[i], 4): kj = tf(keys[i], (0, j)), j = 0..3
  uint32_t k1a,k1b,k2a,k2b,k3a,k3b,k4a,k4b;
  tf2x32(ki0, ki1, 0u, 0u, k1a, k1b);
  tf2x32(ki0, ki1, 0u, 1u, k2a, k2b);
  tf2x32(ki0, ki1, 0u, 2u, k3a, k3b);
  tf2x32(ki0, ki1, 0u, 3u, k4a, k4b);
  uint32_t o0, o1;
  const uint32_t ul = (uint32_t)l;
  tf2x32(k1a, k1b, 0u, ul, o0, o1);  u [i*NB + l] = unif01(o0 ^ o1);
  tf2x32(k2a, k2b, 0u, ul, o0, o1);  rx[i*NB + l] = norm_from_bits(o0 ^ o1);
  tf2x32(k3a, k3b, 0u, ul, o0, o1);  ry[i*NB + l] = norm_from_bits(o0 ^ o1);
  tf2x32(k4a, k4b, 0u, ul, o0, o1);  u2[i*NB + l] = unif01(o0 ^ o1);
}

// ---------------- fp32 GEMM: C(M,N) = A(M,K) @ B(N,K)^T  (+ epilogues) --------
// mode 0: C[m*N+n] = acc + add[m*N+n]
// mode 1: v = tanh(acc + bias1[n]); n<2048 -> C(h), else C2(c)   (N=4096)
// mode 2: C[m*N+n] = acc + bias1[n] + bias2[n]
#define BM 64
#define BN 64
#define BK 16
__global__ __launch_bounds__(256) void gemm_bt(
    const float* __restrict__ A, const float* __restrict__ B,
    int K, int ldb, int N, int mode,
    const float* __restrict__ add,
    const float* __restrict__ bias1, const float* __restrict__ bias2,
    float* __restrict__ C, float* __restrict__ C2)
{
  __shared__ float As[BK][BM];
  __shared__ float Bs[BK][BN];
  const int tid = threadIdx.x;
  const int bm = blockIdx.y * BM;
  const int bn = blockIdx.x * BN;
  const int lr = tid >> 2;          // 0..63
  const int lk = (tid & 3) << 2;    // 0,4,8,12
  const int ty = tid >> 4, tx = tid & 15;
  const int mo = ty << 2, no = tx << 2;
  const bool b_aligned = ((ldb & 3) == 0);
  float acc[4][4] = {{0.f,0.f,0.f,0.f},{0.f,0.f,0.f,0.f},{0.f,0.f,0.f,0.f},{0.f,0.f,0.f,0.f}};

  for (int k0 = 0; k0 < K; k0 += BK) {
    const float* ap = A + (size_t)(bm + lr) * K + (k0 + lk);
    float4 av = *(const float4*)ap;
    As[lk+0][lr] = av.x; As[lk+1][lr] = av.y; As[lk+2][lr] = av.z; As[lk+3][lr] = av.w;
    const float* bp = B + (size_t)(bn + lr) * ldb + (k0 + lk);
    float4 bv;
    if (b_aligned) { bv = *(const float4*)bp; }
    else { bv.x = bp[0]; bv.y = bp[1]; bv.z = bp[2]; bv.w = bp[3]; }
    Bs[lk+0][lr] = bv.x; Bs[lk+1][lr] = bv.y; Bs[lk+2][lr] = bv.z; Bs[lk+3][lr] = bv.w;
    __syncthreads();
#pragma unroll
    for (int k = 0; k < BK; ++k) {
      float4 a = *(const float4*)&As[k][mo];
      float4 b = *(const float4*)&Bs[k][no];
      acc[0][0] = fmaf(a.x, b.x, acc[0][0]);
      acc[0][1] = fmaf(a.x, b.y, acc[0][1]);
      acc[0][2] = fmaf(a.x, b.z, acc[0][2]);
      acc[0][3] = fmaf(a.x, b.w, acc[0][3]);
      acc[1][0] = fmaf(a.y, b.x, acc[1][0]);
      acc[1][1] = fmaf(a.y, b.y, acc[1][1]);
      acc[1][2] = fmaf(a.y, b.z, acc[1][2]);
      acc[1][3] = fmaf(a.y, b.w, acc[1][3]);
      acc[2][0] = fmaf(a.z, b.x, acc[2][0]);
      acc[2][1] = fmaf(a.z, b.y, acc[2][1]);
      acc[2][2] = fmaf(a.z, b.z, acc[2][2]);
      acc[2][3] = fmaf(a.z, b.w, acc[2][3]);
      acc[3][0] = fmaf(a.w, b.x, acc[3][0]);
      acc[3][1] = fmaf(a.w, b.y, acc[3][1]);
      acc[3][2] = fmaf(a.w, b.z, acc[3][2]);
      acc[3][3] = fmaf(a.w, b.w, acc[3][3]);
    }
    __syncthreads();
  }

  const int n0 = bn + no;
#pragma unroll
  for (int i = 0; i < 4; ++i) {
    const int m = bm + mo + i;
    if (mode == 0) {
      float4 adv = *(const float4*)&add[(size_t)m * N + n0];
      float4 r;
      r.x = acc[i][0] + adv.x; r.y = acc[i][1] + adv.y;
      r.z = acc[i][2] + adv.z; r.w = acc[i][3] + adv.w;
      *(float4*)&C[(size_t)m * N + n0] = r;
    } else if (mode == 1) {
      float4 r;
      r.x = tanhf(acc[i][0] + bias1[n0+0]);
      r.y = tanhf(acc[i][1] + bias1[n0+1]);
      r.z = tanhf(acc[i][2] + bias1[n0+2]);
      r.w = tanhf(acc[i][3] + bias1[n0+3]);
      if (n0 < HID) *(float4*)&C [(size_t)m * HID + n0]        = r;
      else          *(float4*)&C2[(size_t)m * HID + (n0-HID)]  = r;
    } else {
      float4 r;
      r.x = acc[i][0] + bias1[n0+0] + bias2[n0+0];
      r.y = acc[i][1] + bias1[n0+1] + bias2[n0+1];
      r.z = acc[i][2] + bias1[n0+2] + bias2[n0+2];
      r.w = acc[i][3] + bias1[n0+3] + bias2[n0+3];
      *(float4*)&C[(size_t)m * N + n0] = r;
    }
  }
}

// ---------------- LSTM elementwise (+ tiny stroke@W_ih[:,128:133] term) ------
__global__ __launch_bounds__(256) void lstm_kernel(
    const float* __restrict__ G, const float* __restrict__ W_ih,
    const float* __restrict__ stroke, float* __restrict__ h, float* __restrict__ c)
{
  int idx = blockIdx.x * 256 + threadIdx.x;   // 0..262143
  int b = idx >> 11, j = idx & 2047;
  const float* st = stroke + b * 5;
  float s0 = st[0], s1 = st[1], s2 = st[2], s3 = st[3], s4 = st[4];
  const float* g = G + (size_t)b * NG;
  float gate[4];
#pragma unroll
  for (int q = 0; q < 4; ++q) {
    int n = q * HID + j;
    const float* w = W_ih + (size_t)n * 133 + 128;
    gate[q] = g[n] + s0*w[0] + s1*w[1] + s2*w[2] + s3*w[3] + s4*w[4];
  }
  float ig = 1.0f / (1.0f + expf(-gate[0]));
  float fg = 1.0f / (1.0f + expf(-gate[1]));
  float gg = tanhf(gate[2]);
  float og = 1.0f / (1.0f + expf(-gate[3]));
  float cn = fg * c[idx] + ig * gg;
  float hn = og * tanhf(cn);
  c[idx] = cn;
  h[idx] = hn;
}

// ---------------- projection: outp(128,63) = h @ proj_w^T + proj_b -----------
__global__ __launch_bounds__(256) void proj_kernel(
    const float* __restrict__ h, const float* __restrict__ w,
    const float* __restrict__ bias, float* __restrict__ outp)
{
  __shared__ float wl[HID];
  int n = blockIdx.x;  // 0..62
  for (int k = threadIdx.x; k < HID; k += 256) wl[k] = w[(size_t)n * HID + k];
  __syncthreads();
  int t = threadIdx.x;
  int b = t >> 1, half = t & 1;
  const float* hp = h + (size_t)b * HID + half * 1024;
  const float* wp = wl + half * 1024;
  float acc = 0.f;
  for (int k = 0; k < 1024; ++k) acc = fmaf(hp[k], wp[k], acc);
  acc += __shfl_xor(acc, 1);
  if (!half) outp[b * ODIM + n] = acc + bias[n];
}

// ---------------- GMM sampling + pen + mask, writes stroke & d_out -----------
__global__ void sample_kernel(const float* __restrict__ outp,
    const int* __restrict__ N_s, const float* __restrict__ u,
    const float* __restrict__ rx, const float* __restrict__ ry,
    const float* __restrict__ u2, int step,
    float* __restrict__ stroke, float* __restrict__ dout)
{
  int b = threadIdx.x;
  if (b >= NB) return;
  const float* o = outp + b * ODIM;
  float xs[10];
  float mx = -3.402823466e+38f;
#pragma unroll
  for (int m = 0; m < 10; ++m) { xs[m] = o[6*m] * 2.0f; mx = fmaxf(mx, xs[m]); }
  float e[10]; float ssum = 0.f;
#pragma unroll
  for (int m = 0; m < 10; ++m) { e[m] = expf(xs[m] - mx); ssum += e[m]; }
  float uu = u[b];
  int cnt = 0; float csum = 0.f;
#pragma unroll
  for (int m = 0; m < 10; ++m) { csum += e[m] / ssum; cnt += (csum < uu) ? 1 : 0; }
  int idx = cnt > 9 ? 9 : cnt;
  float mux = o[6*idx+1], muy = o[6*idx+2];
  float sxg = expf(o[6*idx+3]) * __uint_as_float(0x3F3504F3u); // * sqrt(T)
  float syg = expf(o[6*idx+4]) * __uint_as_float(0x3F3504F3u);
  float rg  = tanhf(o[6*idx+5]);
  float ox = mux + sxg * rx[b];
  float oy = muy + syg * (rg * ox + sqrtf(1.0f - rg*rg) * ry[b]);
  // pen softmax over 3
  float p0 = o[60]*2.0f, p1 = o[61]*2.0f, p2 = o[62]*2.0f;
  float pmx = fmaxf(p0, fmaxf(p1, p2));
  float e0 = expf(p0-pmx), e1 = expf(p1-pmx), e2 = expf(p2-pmx);
  float es = e0+e1+e2;
  float uu2 = u2[b];
  int c2 = 0; float cs = 0.f;
  cs += e0/es; c2 += (cs < uu2) ? 1 : 0;
  cs += e1/es; c2 += (cs < uu2) ? 1 : 0;
  cs += e2/es; c2 += (cs < uu2) ? 1 : 0;
  int pidx = c2 > 2 ? 2 : c2;
  float nx0 = ox, nx1 = oy;
  float nx2 = (pidx==0)?1.f:0.f, nx3 = (pidx==1)?1.f:0.f, nx4 = (pidx==2)?1.f:0.f;
  if (step > N_s[b]) { nx0=0.f; nx1=0.f; nx2=0.f; nx3=0.f; nx4=1.f; }
  float* sp = stroke + b*5;
  sp[0]=nx0; sp[1]=nx1; sp[2]=nx2; sp[3]=nx3; sp[4]=nx4;
  float* dp = dout + b*5;
  dp[0]=nx0; dp[1]=nx1; dp[2]=nx2; dp[3]=nx3; dp[4]=nx4;
}

extern "C" void kernel_launch(void* const* d_in, const int* in_sizes, int n_in,
                              void* d_out, int out_size, void* d_ws, size_t ws_size,
                              hipStream_t stream) {
  const float* z    = (const float*)d_in[0];
  const int*   N_s  = (const int*)  d_in[1];
  const float* fc_w = (const float*)d_in[2];
  const float* fc_b = (const float*)d_in[3];
  const float* W_ih = (const float*)d_in[4];
  const float* W_hh = (const float*)d_in[5];
  const float* b_ih = (const float*)d_in[6];
  const float* b_hh = (const float*)d_in[7];
  const float* pw   = (const float*)d_in[8];
  const float* pb   = (const float*)d_in[9];

  char* ws = (char*)d_ws;
  float* h      = (float*)(ws + 0);
  float* c      = (float*)(ws + 1048576);
  float* gz     = (float*)(ws + 2097152);
  float* G      = (float*)(ws + 6291456);
  float* outp   = (float*)(ws + 10485760);
  float* u      = (float*)(ws + 10518528);
  float* rx     = (float*)(ws + 10523648);
  float* ry     = (float*)(ws + 10528768);
  float* u2     = (float*)(ws + 10533888);
  float* stroke = (float*)(ws + 10539008);
  float* dout   = (float*)d_out;

  rand_kernel<<<dim3(10), dim3(128), 0, stream>>>(u, rx, ry, u2, stroke);
  // hc = tanh(z @ fc_in_w^T + fc_in_b) -> h0 | c0
  gemm_bt<<<dim3(4096/BN, NB/BM), dim3(256), 0, stream>>>(
      z, fc_w, 128, 128, 4096, 1, nullptr, fc_b, nullptr, h, c);
  // gates_z = z @ W_ih[:, :128]^T + b_ih + b_hh
  gemm_bt<<<dim3(NG/BN, NB/BM), dim3(256), 0, stream>>>(
      z, W_ih, 128, 133, NG, 2, nullptr, b_ih, b_hh, gz, nullptr);

  for (int s = 0; s < 10; ++s) {
    gemm_bt<<<dim3(NG/BN, NB/BM), dim3(256), 0, stream>>>(
        h, W_hh, HID, HID, NG, 0, gz, nullptr, nullptr, G, nullptr);
    lstm_kernel<<<dim3(NB*HID/256), dim3(256), 0, stream>>>(G, W_ih, stroke, h, c);
    proj_kernel<<<dim3(ODIM), dim3(256), 0, stream>>>(h, pw, pb, outp);
    sample_kernel<<<dim3(1), dim3(NB), 0, stream>>>(
        outp, N_s, u + s*NB, rx + s*NB, ry + s*NB, u2 + s*NB, s, stroke, dout + s*NB*5);
  }
}

// Round 5
// 1198.893 us; speedup vs baseline: 1.3516x; 1.3516x over previous
//
#include <hip/hip_runtime.h>
#include <stdint.h>
#include <stddef.h>

#define HID 2048
#define NB 128
#define NG 8192
#define ODIM 63

// ---------------- threefry2x32 core (JAX-exact) ----------------
__device__ __forceinline__ void tf2x32(uint32_t k0, uint32_t k1,
                                       uint32_t x0, uint32_t x1,
                                       uint32_t& o0, uint32_t& o1) {
  uint32_t ks2 = k0 ^ k1 ^ 0x1BD11BDAu;
  x0 += k0; x1 += k1;
#define TF_ROTL(v,d) (((v)<<(d))|((v)>>(32-(d))))
#define TF_R(r) { x0 += x1; x1 = TF_ROTL(x1,r); x1 ^= x0; }
  TF_R(13) TF_R(15) TF_R(26) TF_R(6)
  x0 += k1;  x1 += ks2 + 1u;
  TF_R(17) TF_R(29) TF_R(16) TF_R(24)
  x0 += ks2; x1 += k0 + 2u;
  TF_R(13) TF_R(15) TF_R(26) TF_R(6)
  x0 += k0;  x1 += k1 + 3u;
  TF_R(17) TF_R(29) TF_R(16) TF_R(24)
  x0 += k1;  x1 += ks2 + 4u;
  TF_R(13) TF_R(15) TF_R(26) TF_R(6)
  x0 += ks2; x1 += k0 + 5u;
  o0 = x0; o1 = x1;
#undef TF_R
#undef TF_ROTL
}

__device__ __forceinline__ float unif01(uint32_t b) {
  return __uint_as_float((b >> 9) | 0x3f800000u) - 1.0f;
}

// XLA ErfInv (Giles polynomial, f32)
__device__ __forceinline__ float erfinv_xla(float x) {
  float t = x * x;
  float w = -log1pf(-t);
  float p;
  if (w < 5.0f) {
    w = w - 2.5f;
    p = 2.81022636e-08f;
    p = fmaf(p, w, 3.43273939e-07f);
    p = fmaf(p, w, -3.5233877e-06f);
    p = fmaf(p, w, -4.39150654e-06f);
    p = fmaf(p, w, 0.00021858087f);
    p = fmaf(p, w, -0.00125372503f);
    p = fmaf(p, w, -0.00417768164f);
    p = fmaf(p, w, 0.246640727f);
    p = fmaf(p, w, 1.50140941f);
  } else {
    w = sqrtf(w) - 3.0f;
    p = -0.000200214257f;
    p = fmaf(p, w, 0.000100950558f);
    p = fmaf(p, w, 0.00134934322f);
    p = fmaf(p, w, -0.00367342844f);
    p = fmaf(p, w, 0.00573950773f);
    p = fmaf(p, w, -0.0076224613f);
    p = fmaf(p, w, 0.00943887047f);
    p = fmaf(p, w, 1.00167406f);
    p = fmaf(p, w, 2.83297682f);
  }
  return p * x;
}

__device__ __forceinline__ float norm_from_bits(uint32_t b) {
  float f = unif01(b);
  float v = f * 2.0f + __uint_as_float(0xBF7FFFFFu);
  return __uint_as_float(0x3FB504F3u) * erfinv_xla(v); // sqrt(2) f32
}

// Partitionable threefry (JAX >= 0.4.36 default) — verified round 4 (absmax 0.0)
__global__ void rand_kernel(float* __restrict__ u, float* __restrict__ rx,
                            float* __restrict__ ry, float* __restrict__ u2,
                            float* __restrict__ stroke) {
  const int i = blockIdx.x;   // step 0..9
  const int l = threadIdx.x;  // batch element 0..127
  if (i == 0) {
    stroke[l*5+0] = 0.f; stroke[l*5+1] = 0.f; stroke[l*5+2] = 1.f;
    stroke[l*5+3] = 0.f; stroke[l*5+4] = 0.f;
  }
  uint32_t ki0, ki1;
  tf2x32(0u, 42u, 0u, (uint32_t)i, ki0, ki1);
  uint32_t k1a,k1b,k2a,k2b,k3a,k3b,k4a,k4b;
  tf2x32(ki0, ki1, 0u, 0u, k1a, k1b);
  tf2x32(ki0, ki1, 0u, 1u, k2a, k2b);
  tf2x32(ki0, ki1, 0u, 2u, k3a, k3b);
  tf2x32(ki0, ki1, 0u, 3u, k4a, k4b);
  uint32_t o0, o1;
  const uint32_t ul = (uint32_t)l;
  tf2x32(k1a, k1b, 0u, ul, o0, o1);  u [i*NB + l] = unif01(o0 ^ o1);
  tf2x32(k2a, k2b, 0u, ul, o0, o1);  rx[i*NB + l] = norm_from_bits(o0 ^ o1);
  tf2x32(k3a, k3b, 0u, ul, o0, o1);  ry[i*NB + l] = norm_from_bits(o0 ^ o1);
  tf2x32(k4a, k4b, 0u, ul, o0, o1);  u2[i*NB + l] = unif01(o0 ^ o1);
}

// ---------------- fp32 GEMM for the two init matmuls (K=128) -----------------
// mode 1: v = tanh(acc + bias1[n]); n<2048 -> C(h), else C2(c)   (N=4096)
// mode 2: C[m*N+n] = acc + bias1[n] + bias2[n]
#define BM 64
#define BN 64
#define BK 16
__global__ __launch_bounds__(256) void gemm_bt(
    const float* __restrict__ A, const float* __restrict__ B,
    int K, int ldb, int N, int mode,
    const float* __restrict__ bias1, const float* __restrict__ bias2,
    float* __restrict__ C, float* __restrict__ C2)
{
  __shared__ float As[BK][BM];
  __shared__ float Bs[BK][BN];
  const int tid = threadIdx.x;
  const int bm = blockIdx.y * BM;
  const int bn = blockIdx.x * BN;
  const int lr = tid >> 2;          // 0..63
  const int lk = (tid & 3) << 2;    // 0,4,8,12
  const int ty = tid >> 4, tx = tid & 15;
  const int mo = ty << 2, no = tx << 2;
  const bool b_aligned = ((ldb & 3) == 0);
  float acc[4][4] = {{0.f,0.f,0.f,0.f},{0.f,0.f,0.f,0.f},{0.f,0.f,0.f,0.f},{0.f,0.f,0.f,0.f}};

  for (int k0 = 0; k0 < K; k0 += BK) {
    const float* ap = A + (size_t)(bm + lr) * K + (k0 + lk);
    float4 av = *(const float4*)ap;
    As[lk+0][lr] = av.x; As[lk+1][lr] = av.y; As[lk+2][lr] = av.z; As[lk+3][lr] = av.w;
    const float* bp = B + (size_t)(bn + lr) * ldb + (k0 + lk);
    float4 bv;
    if (b_aligned) { bv = *(const float4*)bp; }
    else { bv.x = bp[0]; bv.y = bp[1]; bv.z = bp[2]; bv.w = bp[3]; }
    Bs[lk+0][lr] = bv.x; Bs[lk+1][lr] = bv.y; Bs[lk+2][lr] = bv.z; Bs[lk+3][lr] = bv.w;
    __syncthreads();
#pragma unroll
    for (int k = 0; k < BK; ++k) {
      float4 a = *(const float4*)&As[k][mo];
      float4 b = *(const float4*)&Bs[k][no];
      acc[0][0] = fmaf(a.x, b.x, acc[0][0]);
      acc[0][1] = fmaf(a.x, b.y, acc[0][1]);
      acc[0][2] = fmaf(a.x, b.z, acc[0][2]);
      acc[0][3] = fmaf(a.x, b.w, acc[0][3]);
      acc[1][0] = fmaf(a.y, b.x, acc[1][0]);
      acc[1][1] = fmaf(a.y, b.y, acc[1][1]);
      acc[1][2] = fmaf(a.y, b.z, acc[1][2]);
      acc[1][3] = fmaf(a.y, b.w, acc[1][3]);
      acc[2][0] = fmaf(a.z, b.x, acc[2][0]);
      acc[2][1] = fmaf(a.z, b.y, acc[2][1]);
      acc[2][2] = fmaf(a.z, b.z, acc[2][2]);
      acc[2][3] = fmaf(a.z, b.w, acc[2][3]);
      acc[3][0] = fmaf(a.w, b.x, acc[3][0]);
      acc[3][1] = fmaf(a.w, b.y, acc[3][1]);
      acc[3][2] = fmaf(a.w, b.z, acc[3][2]);
      acc[3][3] = fmaf(a.w, b.w, acc[3][3]);
    }
    __syncthreads();
  }

  const int n0 = bn + no;
#pragma unroll
  for (int i = 0; i < 4; ++i) {
    const int m = bm + mo + i;
    if (mode == 1) {
      float4 r;
      r.x = tanhf(acc[i][0] + bias1[n0+0]);
      r.y = tanhf(acc[i][1] + bias1[n0+1]);
      r.z = tanhf(acc[i][2] + bias1[n0+2]);
      r.w = tanhf(acc[i][3] + bias1[n0+3]);
      if (n0 < HID) *(float4*)&C [(size_t)m * HID + n0]        = r;
      else          *(float4*)&C2[(size_t)m * HID + (n0-HID)]  = r;
    } else {
      float4 r;
      r.x = acc[i][0] + bias1[n0+0] + bias2[n0+0];
      r.y = acc[i][1] + bias1[n0+1] + bias2[n0+1];
      r.z = acc[i][2] + bias1[n0+2] + bias2[n0+2];
      r.w = acc[i][3] + bias1[n0+3] + bias2[n0+3];
      *(float4*)&C[(size_t)m * N + n0] = r;
    }
  }
}

// ------------- recurrent GEMM + fused LSTM epilogue --------------------------
// Block (jc, bmi): covers m = bmi*64..+63, B-rows {g*2048 + jc*16 + jj : g=0..3, jj=0..15}
// K sequential 0..2047 single-accumulator fmaf (bit-identical to old gemm_bt).
// Double-buffered LDS, 1 barrier per 32-k tile, 2-way-max staging bank aliasing.
#define BK2 32
__global__ __launch_bounds__(256) void rec_gemm_lstm(
    const float* __restrict__ A,      // h_cur [128][2048]
    const float* __restrict__ W,      // W_hh  [8192][2048]
    const float* __restrict__ gz,     // [128][8192]  (z-part + b_ih + b_hh)
    const float* __restrict__ W_ih,   // [8192][133]
    const float* __restrict__ stroke, // [128][5]
    float* __restrict__ c,            // [128][2048] in-place
    float* __restrict__ h_next)       // [128][2048]
{
  __shared__ float As[2][BK2][64];
  __shared__ float Bs[2][BK2][64];
  __shared__ float gt[64][68];
  const int tid = threadIdx.x;
  const int jc = blockIdx.x;        // 0..127
  const int bm = blockIdx.y * 64;   // 0 or 64
  const int j0 = jc * 16;

  const int sr = tid & 63;          // staging row 0..63
  const int sk = (tid >> 6) << 3;   // staging k offset: 0,8,16,24
  const int brow = (sr >> 4) * HID + j0 + (sr & 15);
  const int mo = (tid >> 4) << 2;
  const int no = (tid & 15) << 2;

  float acc[4][4] = {{0.f,0.f,0.f,0.f},{0.f,0.f,0.f,0.f},{0.f,0.f,0.f,0.f},{0.f,0.f,0.f,0.f}};

  const float* abase = A + (size_t)(bm + sr) * HID + sk;
  const float* bbase = W + (size_t)brow * HID + sk;

#define STG(bi) do { \
    As[bi][sk+0][sr]=ra0.x; As[bi][sk+1][sr]=ra0.y; As[bi][sk+2][sr]=ra0.z; As[bi][sk+3][sr]=ra0.w; \
    As[bi][sk+4][sr]=ra1.x; As[bi][sk+5][sr]=ra1.y; As[bi][sk+6][sr]=ra1.z; As[bi][sk+7][sr]=ra1.w; \
    Bs[bi][sk+0][sr]=rb0.x; Bs[bi][sk+1][sr]=rb0.y; Bs[bi][sk+2][sr]=rb0.z; Bs[bi][sk+3][sr]=rb0.w; \
    Bs[bi][sk+4][sr]=rb1.x; Bs[bi][sk+5][sr]=rb1.y; Bs[bi][sk+6][sr]=rb1.z; Bs[bi][sk+7][sr]=rb1.w; \
  } while (0)

  float4 ra0 = *(const float4*)(abase);
  float4 ra1 = *(const float4*)(abase + 4);
  float4 rb0 = *(const float4*)(bbase);
  float4 rb1 = *(const float4*)(bbase + 4);
  STG(0);
  __syncthreads();

  int cur = 0;
  for (int t = 0; t < 64; ++t) {
    if (t < 63) {  // issue next-tile loads; latency hidden under compute
      ra0 = *(const float4*)(abase + (t+1)*BK2);
      ra1 = *(const float4*)(abase + (t+1)*BK2 + 4);
      rb0 = *(const float4*)(bbase + (t+1)*BK2);
      rb1 = *(const float4*)(bbase + (t+1)*BK2 + 4);
    }
#pragma unroll
    for (int k = 0; k < BK2; ++k) {
      float4 a = *(const float4*)&As[cur][k][mo];
      float4 b = *(const float4*)&Bs[cur][k][no];
      acc[0][0] = fmaf(a.x, b.x, acc[0][0]);
      acc[0][1] = fmaf(a.x, b.y, acc[0][1]);
      acc[0][2] = fmaf(a.x, b.z, acc[0][2]);
      acc[0][3] = fmaf(a.x, b.w, acc[0][3]);
      acc[1][0] = fmaf(a.y, b.x, acc[1][0]);
      acc[1][1] = fmaf(a.y, b.y, acc[1][1]);
      acc[1][2] = fmaf(a.y, b.z, acc[1][2]);
      acc[1][3] = fmaf(a.y, b.w, acc[1][3]);
      acc[2][0] = fmaf(a.z, b.x, acc[2][0]);
      acc[2][1] = fmaf(a.z, b.y, acc[2][1]);
      acc[2][2] = fmaf(a.z, b.z, acc[2][2]);
      acc[2][3] = fmaf(a.z, b.w, acc[2][3]);
      acc[3][0] = fmaf(a.w, b.x, acc[3][0]);
      acc[3][1] = fmaf(a.w, b.y, acc[3][1]);
      acc[3][2] = fmaf(a.w, b.z, acc[3][2]);
      acc[3][3] = fmaf(a.w, b.w, acc[3][3]);
    }
    if (t < 63) STG(cur ^ 1);
    __syncthreads();
    cur ^= 1;
  }
#undef STG

  // stash gates (+gz) into LDS tile for 4-gate regroup
  const int g = no >> 4;
#pragma unroll
  for (int i = 0; i < 4; ++i) {
    const int m = mo + i;
    float4 gzv = *(const float4*)&gz[(size_t)(bm + m) * NG + g * HID + j0 + (no & 15)];
    gt[m][no+0] = acc[i][0] + gzv.x;
    gt[m][no+1] = acc[i][1] + gzv.y;
    gt[m][no+2] = acc[i][2] + gzv.z;
    gt[m][no+3] = acc[i][3] + gzv.w;
  }
  __syncthreads();

  // LSTM elementwise: 1024 (m,jj) pairs, 4 per thread
#pragma unroll
  for (int p = 0; p < 4; ++p) {
    const int pid = p * 256 + tid;
    const int m  = pid >> 4;
    const int jj = pid & 15;
    const int gm = bm + m;
    const int col = j0 + jj;
    float gv[4];
    gv[0] = gt[m][jj];
    gv[1] = gt[m][16+jj];
    gv[2] = gt[m][32+jj];
    gv[3] = gt[m][48+jj];
    const float* st = stroke + gm*5;
    float s0 = st[0], s1 = st[1], s2 = st[2], s3 = st[3], s4 = st[4];
#pragma unroll
    for (int q = 0; q < 4; ++q) {
      const float* w = W_ih + (size_t)(q * HID + col) * 133 + 128;
      float t0 = gv[q];
      t0 = fmaf(s0, w[0], t0);
      t0 = fmaf(s1, w[1], t0);
      t0 = fmaf(s2, w[2], t0);
      t0 = fmaf(s3, w[3], t0);
      t0 = fmaf(s4, w[4], t0);
      gv[q] = t0;
    }
    float ig = 1.0f / (1.0f + expf(-gv[0]));
    float fg = 1.0f / (1.0f + expf(-gv[1]));
    float gg = tanhf(gv[2]);
    float og = 1.0f / (1.0f + expf(-gv[3]));
    const size_t idx = (size_t)gm * HID + col;
    float cn = fg * c[idx] + ig * gg;
    float hn = og * tanhf(cn);
    c[idx] = cn;
    h_next[idx] = hn;
  }
}

// ------------- fused projection + GMM sampling (one block per batch b) -------
__global__ __launch_bounds__(256) void projsample(
    const float* __restrict__ h, const float* __restrict__ pw,
    const float* __restrict__ pb, const int* __restrict__ N_s,
    const float* __restrict__ u, const float* __restrict__ rx,
    const float* __restrict__ ry, const float* __restrict__ u2, int step,
    float* __restrict__ stroke, float* __restrict__ dout)
{
  __shared__ float hl[4*520];   // 4 parts of 512, skewed by 8 for bank spread
  __shared__ float outs[64];
  const int b = blockIdx.x;
  const int t = threadIdx.x;
  const float* hp = h + (size_t)b * HID;
  {
    const int part = t >> 6;           // t*8 / 512
    const int kk = (t * 8) & 511;
    float4 v0 = *(const float4*)&hp[t*8];
    float4 v1 = *(const float4*)&hp[t*8+4];
    *(float4*)&hl[part*520 + kk]     = v0;
    *(float4*)&hl[part*520 + kk + 4] = v1;
  }
  __syncthreads();
  if (t < 252) {
    const int n = t >> 2, part = t & 3;
    const float* wrow = pw + (size_t)n * HID + part * 512;
    const float* hh = hl + part * 520;
    float acc = 0.f;
#pragma unroll 4
    for (int k = 0; k < 512; k += 4) {
      float4 wv = *(const float4*)&wrow[k];
      float4 hv = *(const float4*)&hh[k];
      acc = fmaf(hv.x, wv.x, acc);
      acc = fmaf(hv.y, wv.y, acc);
      acc = fmaf(hv.z, wv.z, acc);
      acc = fmaf(hv.w, wv.w, acc);
    }
    acc += __shfl_xor(acc, 1);
    acc += __shfl_xor(acc, 2);
    if (part == 0) outs[n] = acc + pb[n];
  }
  __syncthreads();
  if (t == 0) {
    const float* o = outs;
    float xs[10];
    float mx = -3.402823466e+38f;
#pragma unroll
    for (int m = 0; m < 10; ++m) { xs[m] = o[6*m] * 2.0f; mx = fmaxf(mx, xs[m]); }
    float e[10]; float ssum = 0.f;
#pragma unroll
    for (int m = 0; m < 10; ++m) { e[m] = expf(xs[m] - mx); ssum += e[m]; }
    float uu = u[b];
    int cnt = 0; float csum = 0.f;
#pragma unroll
    for (int m = 0; m < 10; ++m) { csum += e[m] / ssum; cnt += (csum < uu) ? 1 : 0; }
    int idx = cnt > 9 ? 9 : cnt;
    float mux = o[6*idx+1], muy = o[6*idx+2];
    float sxg = expf(o[6*idx+3]) * __uint_as_float(0x3F3504F3u); // * sqrt(T)
    float syg = expf(o[6*idx+4]) * __uint_as_float(0x3F3504F3u);
    float rg  = tanhf(o[6*idx+5]);
    float ox = mux + sxg * rx[b];
    float oy = muy + syg * (rg * ox + sqrtf(1.0f - rg*rg) * ry[b]);
    float p0 = o[60]*2.0f, p1 = o[61]*2.0f, p2 = o[62]*2.0f;
    float pmx = fmaxf(p0, fmaxf(p1, p2));
    float e0 = expf(p0-pmx), e1 = expf(p1-pmx), e2 = expf(p2-pmx);
    float es = e0+e1+e2;
    float uu2 = u2[b];
    int c2 = 0; float cs = 0.f;
    cs += e0/es; c2 += (cs < uu2) ? 1 : 0;
    cs += e1/es; c2 += (cs < uu2) ? 1 : 0;
    cs += e2/es; c2 += (cs < uu2) ? 1 : 0;
    int pidx = c2 > 2 ? 2 : c2;
    float nx0 = ox, nx1 = oy;
    float nx2 = (pidx==0)?1.f:0.f, nx3 = (pidx==1)?1.f:0.f, nx4 = (pidx==2)?1.f:0.f;
    if (step > N_s[b]) { nx0=0.f; nx1=0.f; nx2=0.f; nx3=0.f; nx4=1.f; }
    float* sp = stroke + b*5;
    sp[0]=nx0; sp[1]=nx1; sp[2]=nx2; sp[3]=nx3; sp[4]=nx4;
    float* dp = dout + b*5;
    dp[0]=nx0; dp[1]=nx1; dp[2]=nx2; dp[3]=nx3; dp[4]=nx4;
  }
}

extern "C" void kernel_launch(void* const* d_in, const int* in_sizes, int n_in,
                              void* d_out, int out_size, void* d_ws, size_t ws_size,
                              hipStream_t stream) {
  const float* z    = (const float*)d_in[0];
  const int*   N_s  = (const int*)  d_in[1];
  const float* fc_w = (const float*)d_in[2];
  const float* fc_b = (const float*)d_in[3];
  const float* W_ih = (const float*)d_in[4];
  const float* W_hh = (const float*)d_in[5];
  const float* b_ih = (const float*)d_in[6];
  const float* b_hh = (const float*)d_in[7];
  const float* pw   = (const float*)d_in[8];
  const float* pb   = (const float*)d_in[9];

  char* ws = (char*)d_ws;
  float* hA     = (float*)(ws + 0);
  float* c      = (float*)(ws + 1048576);
  float* gz     = (float*)(ws + 2097152);
  float* hB     = (float*)(ws + 6291456);
  float* u      = (float*)(ws + 10518528);
  float* rx     = (float*)(ws + 10523648);
  float* ry     = (float*)(ws + 10528768);
  float* u2     = (float*)(ws + 10533888);
  float* stroke = (float*)(ws + 10539008);
  float* dout   = (float*)d_out;

  rand_kernel<<<dim3(10), dim3(128), 0, stream>>>(u, rx, ry, u2, stroke);
  // hc = tanh(z @ fc_in_w^T + fc_in_b) -> h0 (hA) | c0
  gemm_bt<<<dim3(4096/BN, NB/BM), dim3(256), 0, stream>>>(
      z, fc_w, 128, 128, 4096, 1, fc_b, nullptr, hA, c);
  // gates_z = z @ W_ih[:, :128]^T + b_ih + b_hh
  gemm_bt<<<dim3(NG/BN, NB/BM), dim3(256), 0, stream>>>(
      z, W_ih, 128, 133, NG, 2, b_ih, b_hh, gz, nullptr);

  float* hbuf[2] = { hA, hB };
  for (int s = 0; s < 10; ++s) {
    float* hcur = hbuf[s & 1];
    float* hnxt = hbuf[(s + 1) & 1];
    rec_gemm_lstm<<<dim3(HID/16, NB/64), dim3(256), 0, stream>>>(
        hcur, W_hh, gz, W_ih, stroke, c, hnxt);
    projsample<<<dim3(NB), dim3(256), 0, stream>>>(
        hnxt, pw, pb, N_s, u + s*NB, rx + s*NB, ry + s*NB, u2 + s*NB, s,
        stroke, dout + s*NB*5);
  }
}

// Round 6
// 1020.025 us; speedup vs baseline: 1.5886x; 1.1754x over previous
//
#include <hip/hip_runtime.h>
#include <stdint.h>
#include <stddef.h>

#define HID 2048
#define NB 128
#define NG 8192
#define ODIM 63

typedef unsigned int u32;
typedef unsigned short u16;
typedef short bf16x8 __attribute__((ext_vector_type(8)));
typedef float f32x4 __attribute__((ext_vector_type(4)));

__device__ __forceinline__ u16 f2bf(float x) {          // RNE f32->bf16
  u32 u = __float_as_uint(x);
  return (u16)((u + 0x7FFFu + ((u >> 16) & 1u)) >> 16);
}
__device__ __forceinline__ float bf2f(u16 b) {
  return __uint_as_float(((u32)b) << 16);
}

// ---------------- threefry2x32 core (JAX-exact) ----------------
__device__ __forceinline__ void tf2x32(u32 k0, u32 k1, u32 x0, u32 x1,
                                       u32& o0, u32& o1) {
  u32 ks2 = k0 ^ k1 ^ 0x1BD11BDAu;
  x0 += k0; x1 += k1;
#define TF_ROTL(v,d) (((v)<<(d))|((v)>>(32-(d))))
#define TF_R(r) { x0 += x1; x1 = TF_ROTL(x1,r); x1 ^= x0; }
  TF_R(13) TF_R(15) TF_R(26) TF_R(6)
  x0 += k1;  x1 += ks2 + 1u;
  TF_R(17) TF_R(29) TF_R(16) TF_R(24)
  x0 += ks2; x1 += k0 + 2u;
  TF_R(13) TF_R(15) TF_R(26) TF_R(6)
  x0 += k0;  x1 += k1 + 3u;
  TF_R(17) TF_R(29) TF_R(16) TF_R(24)
  x0 += k1;  x1 += ks2 + 4u;
  TF_R(13) TF_R(15) TF_R(26) TF_R(6)
  x0 += ks2; x1 += k0 + 5u;
  o0 = x0; o1 = x1;
#undef TF_R
#undef TF_ROTL
}

__device__ __forceinline__ float unif01(u32 b) {
  return __uint_as_float((b >> 9) | 0x3f800000u) - 1.0f;
}

__device__ __forceinline__ float erfinv_xla(float x) {
  float t = x * x;
  float w = -log1pf(-t);
  float p;
  if (w < 5.0f) {
    w = w - 2.5f;
    p = 2.81022636e-08f;
    p = fmaf(p, w, 3.43273939e-07f);
    p = fmaf(p, w, -3.5233877e-06f);
    p = fmaf(p, w, -4.39150654e-06f);
    p = fmaf(p, w, 0.00021858087f);
    p = fmaf(p, w, -0.00125372503f);
    p = fmaf(p, w, -0.00417768164f);
    p = fmaf(p, w, 0.246640727f);
    p = fmaf(p, w, 1.50140941f);
  } else {
    w = sqrtf(w) - 3.0f;
    p = -0.000200214257f;
    p = fmaf(p, w, 0.000100950558f);
    p = fmaf(p, w, 0.00134934322f);
    p = fmaf(p, w, -0.00367342844f);
    p = fmaf(p, w, 0.00573950773f);
    p = fmaf(p, w, -0.0076224613f);
    p = fmaf(p, w, 0.00943887047f);
    p = fmaf(p, w, 1.00167406f);
    p = fmaf(p, w, 2.83297682f);
  }
  return p * x;
}

__device__ __forceinline__ float norm_from_bits(u32 b) {
  float f = unif01(b);
  float v = f * 2.0f + __uint_as_float(0xBF7FFFFFu);
  return __uint_as_float(0x3FB504F3u) * erfinv_xla(v); // sqrt(2) f32
}

// Partitionable threefry (JAX >= 0.4.36) — verified round 4/5 (absmax 0.0)
__global__ void rand_kernel(float* __restrict__ u, float* __restrict__ rx,
                            float* __restrict__ ry, float* __restrict__ u2,
                            float* __restrict__ stroke) {
  const int i = blockIdx.x;   // step 0..9
  const int l = threadIdx.x;  // batch 0..127
  if (i == 0) {
    stroke[l*5+0] = 0.f; stroke[l*5+1] = 0.f; stroke[l*5+2] = 1.f;
    stroke[l*5+3] = 0.f; stroke[l*5+4] = 0.f;
  }
  u32 ki0, ki1;
  tf2x32(0u, 42u, 0u, (u32)i, ki0, ki1);
  u32 k1a,k1b,k2a,k2b,k3a,k3b,k4a,k4b;
  tf2x32(ki0, ki1, 0u, 0u, k1a, k1b);
  tf2x32(ki0, ki1, 0u, 1u, k2a, k2b);
  tf2x32(ki0, ki1, 0u, 2u, k3a, k3b);
  tf2x32(ki0, ki1, 0u, 3u, k4a, k4b);
  u32 o0, o1;
  const u32 ul = (u32)l;
  tf2x32(k1a, k1b, 0u, ul, o0, o1);  u [i*NB + l] = unif01(o0 ^ o1);
  tf2x32(k2a, k2b, 0u, ul, o0, o1);  rx[i*NB + l] = norm_from_bits(o0 ^ o1);
  tf2x32(k3a, k3b, 0u, ul, o0, o1);  ry[i*NB + l] = norm_from_bits(o0 ^ o1);
  tf2x32(k4a, k4b, 0u, ul, o0, o1);  u2[i*NB + l] = unif01(o0 ^ o1);
}

// -------- split W_hh (fp32) -> bf16 hi + bf16 lo(residual), 16.78M elems ----
__global__ __launch_bounds__(256) void w_split(const float* __restrict__ W,
                                               u16* __restrict__ Whi,
                                               u16* __restrict__ Wlo) {
  const int i8 = (blockIdx.x * 256 + threadIdx.x) * 8;
  float4 v0 = *(const float4*)&W[i8];
  float4 v1 = *(const float4*)&W[i8 + 4];
  float v[8] = {v0.x, v0.y, v0.z, v0.w, v1.x, v1.y, v1.z, v1.w};
  u32 hp[4], lp[4];
#pragma unroll
  for (int j = 0; j < 4; ++j) {
    u16 h0 = f2bf(v[2*j]),   l0 = f2bf(v[2*j]   - bf2f(h0));
    u16 h1 = f2bf(v[2*j+1]), l1 = f2bf(v[2*j+1] - bf2f(h1));
    hp[j] = (u32)h0 | ((u32)h1 << 16);
    lp[j] = (u32)l0 | ((u32)l1 << 16);
  }
  *(uint4*)&Whi[i8] = make_uint4(hp[0], hp[1], hp[2], hp[3]);
  *(uint4*)&Wlo[i8] = make_uint4(lp[0], lp[1], lp[2], lp[3]);
}

// ---------------- fp32 GEMM for the two init matmuls (K=128) -----------------
// mode 1: v = tanh(acc + bias1[n]); n<2048 -> C(h) (+ optional bf16 hi/lo), else C2(c)
// mode 2: C[m*N+n] = acc + bias1[n] + bias2[n]
#define BM 64
#define BN 64
#define BK 16
__global__ __launch_bounds__(256) void gemm_bt(
    const float* __restrict__ A, const float* __restrict__ B,
    int K, int ldb, int N, int mode,
    const float* __restrict__ bias1, const float* __restrict__ bias2,
    float* __restrict__ C, float* __restrict__ C2,
    u16* __restrict__ Chi, u16* __restrict__ Clo)
{
  __shared__ float As[BK][BM];
  __shared__ float Bs[BK][BN];
  const int tid = threadIdx.x;
  const int bm = blockIdx.y * BM;
  const int bn = blockIdx.x * BN;
  const int lr = tid >> 2;
  const int lk = (tid & 3) << 2;
  const int ty = tid >> 4, tx = tid & 15;
  const int mo = ty << 2, no = tx << 2;
  const bool b_aligned = ((ldb & 3) == 0);
  float acc[4][4] = {{0.f,0.f,0.f,0.f},{0.f,0.f,0.f,0.f},{0.f,0.f,0.f,0.f},{0.f,0.f,0.f,0.f}};

  for (int k0 = 0; k0 < K; k0 += BK) {
    const float* ap = A + (size_t)(bm + lr) * K + (k0 + lk);
    float4 av = *(const float4*)ap;
    As[lk+0][lr] = av.x; As[lk+1][lr] = av.y; As[lk+2][lr] = av.z; As[lk+3][lr] = av.w;
    const float* bp = B + (size_t)(bn + lr) * ldb + (k0 + lk);
    float4 bv;
    if (b_aligned) { bv = *(const float4*)bp; }
    else { bv.x = bp[0]; bv.y = bp[1]; bv.z = bp[2]; bv.w = bp[3]; }
    Bs[lk+0][lr] = bv.x; Bs[lk+1][lr] = bv.y; Bs[lk+2][lr] = bv.z; Bs[lk+3][lr] = bv.w;
    __syncthreads();
#pragma unroll
    for (int k = 0; k < BK; ++k) {
      float4 a = *(const float4*)&As[k][mo];
      float4 b = *(const float4*)&Bs[k][no];
      acc[0][0] = fmaf(a.x, b.x, acc[0][0]);
      acc[0][1] = fmaf(a.x, b.y, acc[0][1]);
      acc[0][2] = fmaf(a.x, b.z, acc[0][2]);
      acc[0][3] = fmaf(a.x, b.w, acc[0][3]);
      acc[1][0] = fmaf(a.y, b.x, acc[1][0]);
      acc[1][1] = fmaf(a.y, b.y, acc[1][1]);
      acc[1][2] = fmaf(a.y, b.z, acc[1][2]);
      acc[1][3] = fmaf(a.y, b.w, acc[1][3]);
      acc[2][0] = fmaf(a.z, b.x, acc[2][0]);
      acc[2][1] = fmaf(a.z, b.y, acc[2][1]);
      acc[2][2] = fmaf(a.z, b.z, acc[2][2]);
      acc[2][3] = fmaf(a.z, b.w, acc[2][3]);
      acc[3][0] = fmaf(a.w, b.x, acc[3][0]);
      acc[3][1] = fmaf(a.w, b.y, acc[3][1]);
      acc[3][2] = fmaf(a.w, b.z, acc[3][2]);
      acc[3][3] = fmaf(a.w, b.w, acc[3][3]);
    }
    __syncthreads();
  }

  const int n0 = bn + no;
#pragma unroll
  for (int i = 0; i < 4; ++i) {
    const int m = bm + mo + i;
    if (mode == 1) {
      float4 r;
      r.x = tanhf(acc[i][0] + bias1[n0+0]);
      r.y = tanhf(acc[i][1] + bias1[n0+1]);
      r.z = tanhf(acc[i][2] + bias1[n0+2]);
      r.w = tanhf(acc[i][3] + bias1[n0+3]);
      if (n0 < HID) {
        *(float4*)&C[(size_t)m * HID + n0] = r;
        if (Chi) {
          float rv[4] = {r.x, r.y, r.z, r.w};
          u32 hp[2], lp[2];
#pragma unroll
          for (int j = 0; j < 2; ++j) {
            u16 h0 = f2bf(rv[2*j]),   l0 = f2bf(rv[2*j]   - bf2f(h0));
            u16 h1 = f2bf(rv[2*j+1]), l1 = f2bf(rv[2*j+1] - bf2f(h1));
            hp[j] = (u32)h0 | ((u32)h1 << 16);
            lp[j] = (u32)l0 | ((u32)l1 << 16);
          }
          *(uint2*)&Chi[(size_t)m * HID + n0] = make_uint2(hp[0], hp[1]);
          *(uint2*)&Clo[(size_t)m * HID + n0] = make_uint2(lp[0], lp[1]);
        }
      } else {
        *(float4*)&C2[(size_t)m * HID + (n0-HID)] = r;
      }
    } else {
      float4 r;
      r.x = acc[i][0] + bias1[n0+0] + bias2[n0+0];
      r.y = acc[i][1] + bias1[n0+1] + bias2[n0+1];
      r.z = acc[i][2] + bias1[n0+2] + bias2[n0+2];
      r.w = acc[i][3] + bias1[n0+3] + bias2[n0+3];
      *(float4*)&C[(size_t)m * N + n0] = r;
    }
  }
}

// ------------- MFMA split-bf16 recurrent GEMM + fused LSTM -------------------
// Block (jc, mb): m in [mb*32, +32), gate cols j in [jc*32, +32) for all 4 gates.
// Wave w = gate w: 2 m-tiles x 2 n-tiles of 16x16x32 MFMA, K = 2048 sequential.
// acc = hi*hi + hi*lo + lo*hi (fp32 accum). No LDS in K-loop (frags direct
// from global; B shared 4x across waves via L1). LDS only for gate exchange.
__global__ __launch_bounds__(256) void rec_mfma_lstm(
    const u16* __restrict__ hHi, const u16* __restrict__ hLo,   // [128][2048]
    const u16* __restrict__ WHi, const u16* __restrict__ WLo,   // [8192][2048]
    const float* __restrict__ gz,     // [128][8192]
    const float* __restrict__ W_ih,   // [8192][133]
    const float* __restrict__ stroke, // [128][5]
    float* __restrict__ c,            // [128][2048] in-place
    float* __restrict__ h_next,       // [128][2048]
    u16* __restrict__ hHiN, u16* __restrict__ hLoN)
{
  __shared__ float gt[4][32][33];
  const int tid = threadIdx.x;
  const int jc = blockIdx.x;    // 0..63
  const int mb = blockIdx.y;    // 0..3
  const int g  = tid >> 6;      // wave -> gate
  const int l  = tid & 63;
  const int lr = l & 15;        // fragment row/col within tile
  const int lk = (l >> 4) * 8;  // k-slice

  f32x4 acc00 = {0.f,0.f,0.f,0.f}, acc01 = {0.f,0.f,0.f,0.f};
  f32x4 acc10 = {0.f,0.f,0.f,0.f}, acc11 = {0.f,0.f,0.f,0.f};

  const u16* pa0h = hHi + (size_t)(mb*32 +      lr) * HID + lk;
  const u16* pa1h = hHi + (size_t)(mb*32 + 16 + lr) * HID + lk;
  const u16* pa0l = hLo + (size_t)(mb*32 +      lr) * HID + lk;
  const u16* pa1l = hLo + (size_t)(mb*32 + 16 + lr) * HID + lk;
  const size_t bn0 = (size_t)(g*HID + jc*32 +      lr) * HID + lk;
  const size_t bn1 = (size_t)(g*HID + jc*32 + 16 + lr) * HID + lk;
  const u16* pb0h = WHi + bn0;
  const u16* pb1h = WHi + bn1;
  const u16* pb0l = WLo + bn0;
  const u16* pb1l = WLo + bn1;

#pragma unroll 2
  for (int k0 = 0; k0 < HID; k0 += 32) {
    bf16x8 a0h = *(const bf16x8*)(pa0h + k0);
    bf16x8 a1h = *(const bf16x8*)(pa1h + k0);
    bf16x8 a0l = *(const bf16x8*)(pa0l + k0);
    bf16x8 a1l = *(const bf16x8*)(pa1l + k0);
    bf16x8 b0h = *(const bf16x8*)(pb0h + k0);
    bf16x8 b1h = *(const bf16x8*)(pb1h + k0);
    bf16x8 b0l = *(const bf16x8*)(pb0l + k0);
    bf16x8 b1l = *(const bf16x8*)(pb1l + k0);
    acc00 = __builtin_amdgcn_mfma_f32_16x16x32_bf16(a0h, b0h, acc00, 0, 0, 0);
    acc00 = __builtin_amdgcn_mfma_f32_16x16x32_bf16(a0h, b0l, acc00, 0, 0, 0);
    acc00 = __builtin_amdgcn_mfma_f32_16x16x32_bf16(a0l, b0h, acc00, 0, 0, 0);
    acc01 = __builtin_amdgcn_mfma_f32_16x16x32_bf16(a0h, b1h, acc01, 0, 0, 0);
    acc01 = __builtin_amdgcn_mfma_f32_16x16x32_bf16(a0h, b1l, acc01, 0, 0, 0);
    acc01 = __builtin_amdgcn_mfma_f32_16x16x32_bf16(a0l, b1h, acc01, 0, 0, 0);
    acc10 = __builtin_amdgcn_mfma_f32_16x16x32_bf16(a1h, b0h, acc10, 0, 0, 0);
    acc10 = __builtin_amdgcn_mfma_f32_16x16x32_bf16(a1h, b0l, acc10, 0, 0, 0);
    acc10 = __builtin_amdgcn_mfma_f32_16x16x32_bf16(a1l, b0h, acc10, 0, 0, 0);
    acc11 = __builtin_amdgcn_mfma_f32_16x16x32_bf16(a1h, b1h, acc11, 0, 0, 0);
    acc11 = __builtin_amdgcn_mfma_f32_16x16x32_bf16(a1h, b1l, acc11, 0, 0, 0);
    acc11 = __builtin_amdgcn_mfma_f32_16x16x32_bf16(a1l, b1h, acc11, 0, 0, 0);
  }

  // C/D layout (m89-verified): col = lane&15, row = (lane>>4)*4 + reg
  {
    const int rr = (l >> 4) * 4;
#pragma unroll
    for (int r = 0; r < 4; ++r) {
      gt[g][ 0 + rr + r][ 0 + lr] = acc00[r];
      gt[g][ 0 + rr + r][16 + lr] = acc01[r];
      gt[g][16 + rr + r][ 0 + lr] = acc10[r];
      gt[g][16 + rr + r][16 + lr] = acc11[r];
    }
  }
  __syncthreads();

  // LSTM elementwise: thread -> (m = tid>>3, 4 cols at j4 = (tid&7)*4)
  const int m  = tid >> 3;
  const int j4 = (tid & 7) * 4;
  const int gm = mb*32 + m;
  const int col = jc*32 + j4;
  float gv[4][4];
#pragma unroll
  for (int q = 0; q < 4; ++q) {
    float4 z4 = *(const float4*)&gz[(size_t)gm * NG + q * HID + col];
    gv[q][0] = z4.x + gt[q][m][j4+0];
    gv[q][1] = z4.y + gt[q][m][j4+1];
    gv[q][2] = z4.z + gt[q][m][j4+2];
    gv[q][3] = z4.w + gt[q][m][j4+3];
  }
  const float* st = stroke + gm*5;
  float s0 = st[0], s1 = st[1], s2 = st[2], s3 = st[3], s4 = st[4];
#pragma unroll
  for (int q = 0; q < 4; ++q) {
#pragma unroll
    for (int i = 0; i < 4; ++i) {
      const float* w = W_ih + (size_t)(q * HID + col + i) * 133 + 128;
      float t0 = gv[q][i];
      t0 = fmaf(s0, w[0], t0);
      t0 = fmaf(s1, w[1], t0);
      t0 = fmaf(s2, w[2], t0);
      t0 = fmaf(s3, w[3], t0);
      t0 = fmaf(s4, w[4], t0);
      gv[q][i] = t0;
    }
  }
  const size_t cidx = (size_t)gm * HID + col;
  float4 cv = *(float4*)&c[cidx];
  float cin[4] = {cv.x, cv.y, cv.z, cv.w};
  float hn[4], cn[4];
#pragma unroll
  for (int i = 0; i < 4; ++i) {
    float ig = 1.0f / (1.0f + expf(-gv[0][i]));
    float fg = 1.0f / (1.0f + expf(-gv[1][i]));
    float gg = tanhf(gv[2][i]);
    float og = 1.0f / (1.0f + expf(-gv[3][i]));
    cn[i] = fg * cin[i] + ig * gg;
    hn[i] = og * tanhf(cn[i]);
  }
  *(float4*)&c[cidx]      = make_float4(cn[0], cn[1], cn[2], cn[3]);
  *(float4*)&h_next[cidx] = make_float4(hn[0], hn[1], hn[2], hn[3]);
  u32 hp[2], lp[2];
#pragma unroll
  for (int j = 0; j < 2; ++j) {
    u16 h0 = f2bf(hn[2*j]),   l0 = f2bf(hn[2*j]   - bf2f(h0));
    u16 h1 = f2bf(hn[2*j+1]), l1 = f2bf(hn[2*j+1] - bf2f(h1));
    hp[j] = (u32)h0 | ((u32)h1 << 16);
    lp[j] = (u32)l0 | ((u32)l1 << 16);
  }
  *(uint2*)&hHiN[cidx] = make_uint2(hp[0], hp[1]);
  *(uint2*)&hLoN[cidx] = make_uint2(lp[0], lp[1]);
}

// ------------- fp32 fallback recurrent GEMM + fused LSTM (round 5) ----------
#define BK2 32
__global__ __launch_bounds__(256) void rec_gemm_lstm(
    const float* __restrict__ A, const float* __restrict__ W,
    const float* __restrict__ gz, const float* __restrict__ W_ih,
    const float* __restrict__ stroke, float* __restrict__ c,
    float* __restrict__ h_next)
{
  __shared__ float As[2][BK2][64];
  __shared__ float Bs[2][BK2][64];
  __shared__ float gt[64][68];
  const int tid = threadIdx.x;
  const int jc = blockIdx.x;
  const int bm = blockIdx.y * 64;
  const int j0 = jc * 16;
  const int sr = tid & 63;
  const int sk = (tid >> 6) << 3;
  const int brow = (sr >> 4) * HID + j0 + (sr & 15);
  const int mo = (tid >> 4) << 2;
  const int no = (tid & 15) << 2;
  float acc[4][4] = {{0.f,0.f,0.f,0.f},{0.f,0.f,0.f,0.f},{0.f,0.f,0.f,0.f},{0.f,0.f,0.f,0.f}};
  const float* abase = A + (size_t)(bm + sr) * HID + sk;
  const float* bbase = W + (size_t)brow * HID + sk;
#define STG(bi) do { \
    As[bi][sk+0][sr]=ra0.x; As[bi][sk+1][sr]=ra0.y; As[bi][sk+2][sr]=ra0.z; As[bi][sk+3][sr]=ra0.w; \
    As[bi][sk+4][sr]=ra1.x; As[bi][sk+5][sr]=ra1.y; As[bi][sk+6][sr]=ra1.z; As[bi][sk+7][sr]=ra1.w; \
    Bs[bi][sk+0][sr]=rb0.x; Bs[bi][sk+1][sr]=rb0.y; Bs[bi][sk+2][sr]=rb0.z; Bs[bi][sk+3][sr]=rb0.w; \
    Bs[bi][sk+4][sr]=rb1.x; Bs[bi][sk+5][sr]=rb1.y; Bs[bi][sk+6][sr]=rb1.z; Bs[bi][sk+7][sr]=rb1.w; \
  } while (0)
  float4 ra0 = *(const float4*)(abase);
  float4 ra1 = *(const float4*)(abase + 4);
  float4 rb0 = *(const float4*)(bbase);
  float4 rb1 = *(const float4*)(bbase + 4);
  STG(0);
  __syncthreads();
  int cur = 0;
  for (int t = 0; t < 64; ++t) {
    if (t < 63) {
      ra0 = *(const float4*)(abase + (t+1)*BK2);
      ra1 = *(const float4*)(abase + (t+1)*BK2 + 4);
      rb0 = *(const float4*)(bbase + (t+1)*BK2);
      rb1 = *(const float4*)(bbase + (t+1)*BK2 + 4);
    }
#pragma unroll
    for (int k = 0; k < BK2; ++k) {
      float4 a = *(const float4*)&As[cur][k][mo];
      float4 b = *(const float4*)&Bs[cur][k][no];
      acc[0][0] = fmaf(a.x, b.x, acc[0][0]);
      acc[0][1] = fmaf(a.x, b.y, acc[0][1]);
      acc[0][2] = fmaf(a.x, b.z, acc[0][2]);
      acc[0][3] = fmaf(a.x, b.w, acc[0][3]);
      acc[1][0] = fmaf(a.y, b.x, acc[1][0]);
      acc[1][1] = fmaf(a.y, b.y, acc[1][1]);
      acc[1][2] = fmaf(a.y, b.z, acc[1][2]);
      acc[1][3] = fmaf(a.y, b.w, acc[1][3]);
      acc[2][0] = fmaf(a.z, b.x, acc[2][0]);
      acc[2][1] = fmaf(a.z, b.y, acc[2][1]);
      acc[2][2] = fmaf(a.z, b.z, acc[2][2]);
      acc[2][3] = fmaf(a.z, b.w, acc[2][3]);
      acc[3][0] = fmaf(a.w, b.x, acc[3][0]);
      acc[3][1] = fmaf(a.w, b.y, acc[3][1]);
      acc[3][2] = fmaf(a.w, b.z, acc[3][2]);
      acc[3][3] = fmaf(a.w, b.w, acc[3][3]);
    }
    if (t < 63) STG(cur ^ 1);
    __syncthreads();
    cur ^= 1;
  }
#undef STG
  const int g = no >> 4;
#pragma unroll
  for (int i = 0; i < 4; ++i) {
    const int m = mo + i;
    float4 gzv = *(const float4*)&gz[(size_t)(bm + m) * NG + g * HID + j0 + (no & 15)];
    gt[m][no+0] = acc[i][0] + gzv.x;
    gt[m][no+1] = acc[i][1] + gzv.y;
    gt[m][no+2] = acc[i][2] + gzv.z;
    gt[m][no+3] = acc[i][3] + gzv.w;
  }
  __syncthreads();
#pragma unroll
  for (int p = 0; p < 4; ++p) {
    const int pid = p * 256 + tid;
    const int m  = pid >> 4;
    const int jj = pid & 15;
    const int gm = bm + m;
    const int col = j0 + jj;
    float gv[4];
    gv[0] = gt[m][jj];
    gv[1] = gt[m][16+jj];
    gv[2] = gt[m][32+jj];
    gv[3] = gt[m][48+jj];
    const float* st = stroke + gm*5;
    float s0 = st[0], s1 = st[1], s2 = st[2], s3 = st[3], s4 = st[4];
#pragma unroll
    for (int q = 0; q < 4; ++q) {
      const float* w = W_ih + (size_t)(q * HID + col) * 133 + 128;
      float t0 = gv[q];
      t0 = fmaf(s0, w[0], t0);
      t0 = fmaf(s1, w[1], t0);
      t0 = fmaf(s2, w[2], t0);
      t0 = fmaf(s3, w[3], t0);
      t0 = fmaf(s4, w[4], t0);
      gv[q] = t0;
    }
    float ig = 1.0f / (1.0f + expf(-gv[0]));
    float fg = 1.0f / (1.0f + expf(-gv[1]));
    float gg = tanhf(gv[2]);
    float og = 1.0f / (1.0f + expf(-gv[3]));
    const size_t idx = (size_t)gm * HID + col;
    float cn = fg * c[idx] + ig * gg;
    float hnv = og * tanhf(cn);
    c[idx] = cn;
    h_next[idx] = hnv;
  }
}

// ------------- fused projection + GMM sampling (one block per batch b) -------
__global__ __launch_bounds__(256) void projsample(
    const float* __restrict__ h, const float* __restrict__ pw,
    const float* __restrict__ pb, const int* __restrict__ N_s,
    const float* __restrict__ u, const float* __restrict__ rx,
    const float* __restrict__ ry, const float* __restrict__ u2, int step,
    float* __restrict__ stroke, float* __restrict__ dout)
{
  __shared__ float hl[4*520];
  __shared__ float outs[64];
  const int b = blockIdx.x;
  const int t = threadIdx.x;
  const float* hp = h + (size_t)b * HID;
  {
    const int part = t >> 6;
    const int kk = (t * 8) & 511;
    float4 v0 = *(const float4*)&hp[t*8];
    float4 v1 = *(const float4*)&hp[t*8+4];
    *(float4*)&hl[part*520 + kk]     = v0;
    *(float4*)&hl[part*520 + kk + 4] = v1;
  }
  __syncthreads();
  if (t < 252) {
    const int n = t >> 2, part = t & 3;
    const float* wrow = pw + (size_t)n * HID + part * 512;
    const float* hh = hl + part * 520;
    float acc = 0.f;
#pragma unroll 4
    for (int k = 0; k < 512; k += 4) {
      float4 wv = *(const float4*)&wrow[k];
      float4 hv = *(const float4*)&hh[k];
      acc = fmaf(hv.x, wv.x, acc);
      acc = fmaf(hv.y, wv.y, acc);
      acc = fmaf(hv.z, wv.z, acc);
      acc = fmaf(hv.w, wv.w, acc);
    }
    acc += __shfl_xor(acc, 1);
    acc += __shfl_xor(acc, 2);
    if (part == 0) outs[n] = acc + pb[n];
  }
  __syncthreads();
  if (t == 0) {
    const float* o = outs;
    float xs[10];
    float mx = -3.402823466e+38f;
#pragma unroll
    for (int m = 0; m < 10; ++m) { xs[m] = o[6*m] * 2.0f; mx = fmaxf(mx, xs[m]); }
    float e[10]; float ssum = 0.f;
#pragma unroll
    for (int m = 0; m < 10; ++m) { e[m] = expf(xs[m] - mx); ssum += e[m]; }
    float uu = u[b];
    int cnt = 0; float csum = 0.f;
#pragma unroll
    for (int m = 0; m < 10; ++m) { csum += e[m] / ssum; cnt += (csum < uu) ? 1 : 0; }
    int idx = cnt > 9 ? 9 : cnt;
    float mux = o[6*idx+1], muy = o[6*idx+2];
    float sxg = expf(o[6*idx+3]) * __uint_as_float(0x3F3504F3u);
    float syg = expf(o[6*idx+4]) * __uint_as_float(0x3F3504F3u);
    float rg  = tanhf(o[6*idx+5]);
    float ox = mux + sxg * rx[b];
    float oy = muy + syg * (rg * ox + sqrtf(1.0f - rg*rg) * ry[b]);
    float p0 = o[60]*2.0f, p1 = o[61]*2.0f, p2 = o[62]*2.0f;
    float pmx = fmaxf(p0, fmaxf(p1, p2));
    float e0 = expf(p0-pmx), e1 = expf(p1-pmx), e2 = expf(p2-pmx);
    float es = e0+e1+e2;
    float uu2 = u2[b];
    int c2 = 0; float cs = 0.f;
    cs += e0/es; c2 += (cs < uu2) ? 1 : 0;
    cs += e1/es; c2 += (cs < uu2) ? 1 : 0;
    cs += e2/es; c2 += (cs < uu2) ? 1 : 0;
    int pidx = c2 > 2 ? 2 : c2;
    float nx0 = ox, nx1 = oy;
    float nx2 = (pidx==0)?1.f:0.f, nx3 = (pidx==1)?1.f:0.f, nx4 = (pidx==2)?1.f:0.f;
    if (step > N_s[b]) { nx0=0.f; nx1=0.f; nx2=0.f; nx3=0.f; nx4=1.f; }
    float* sp = stroke + b*5;
    sp[0]=nx0; sp[1]=nx1; sp[2]=nx2; sp[3]=nx3; sp[4]=nx4;
    float* dp = dout + b*5;
    dp[0]=nx0; dp[1]=nx1; dp[2]=nx2; dp[3]=nx3; dp[4]=nx4;
  }
}

extern "C" void kernel_launch(void* const* d_in, const int* in_sizes, int n_in,
                              void* d_out, int out_size, void* d_ws, size_t ws_size,
                              hipStream_t stream) {
  const float* z    = (const float*)d_in[0];
  const int*   N_s  = (const int*)  d_in[1];
  const float* fc_w = (const float*)d_in[2];
  const float* fc_b = (const float*)d_in[3];
  const float* W_ih = (const float*)d_in[4];
  const float* W_hh = (const float*)d_in[5];
  const float* b_ih = (const float*)d_in[6];
  const float* b_hh = (const float*)d_in[7];
  const float* pw   = (const float*)d_in[8];
  const float* pb   = (const float*)d_in[9];

  char* ws = (char*)d_ws;
  float* hA     = (float*)(ws + 0);
  float* c      = (float*)(ws + 1048576);
  float* gz     = (float*)(ws + 2097152);
  float* hB     = (float*)(ws + 6291456);
  float* u      = (float*)(ws + 10518528);
  float* rx     = (float*)(ws + 10523648);
  float* ry     = (float*)(ws + 10528768);
  float* u2     = (float*)(ws + 10533888);
  float* stroke = (float*)(ws + 10539008);
  u16*   Whi    = (u16*)(ws + 11534336);
  u16*   Wlo    = (u16*)(ws + 45088768);
  u16*   hHiA   = (u16*)(ws + 78643200);
  u16*   hLoA   = (u16*)(ws + 79167488);
  u16*   hHiB   = (u16*)(ws + 79691776);
  u16*   hLoB   = (u16*)(ws + 80216064);
  float* dout   = (float*)d_out;

  const bool fast = (ws_size >= 80740352ull);

  rand_kernel<<<dim3(10), dim3(128), 0, stream>>>(u, rx, ry, u2, stroke);
  gemm_bt<<<dim3(4096/BN, NB/BM), dim3(256), 0, stream>>>(
      z, fc_w, 128, 128, 4096, 1, fc_b, nullptr, hA, c,
      fast ? hHiA : nullptr, fast ? hLoA : nullptr);
  gemm_bt<<<dim3(NG/BN, NB/BM), dim3(256), 0, stream>>>(
      z, W_ih, 128, 133, NG, 2, b_ih, b_hh, gz, nullptr, nullptr, nullptr);

  if (fast) {
    w_split<<<dim3(8192), dim3(256), 0, stream>>>(W_hh, Whi, Wlo);
    u16* hhi[2] = { hHiA, hHiB };
    u16* hlo[2] = { hLoA, hLoB };
    float* hbuf[2] = { hA, hB };
    for (int s = 0; s < 10; ++s) {
      rec_mfma_lstm<<<dim3(64, 4), dim3(256), 0, stream>>>(
          hhi[s & 1], hlo[s & 1], Whi, Wlo, gz, W_ih, stroke, c,
          hbuf[(s + 1) & 1], hhi[(s + 1) & 1], hlo[(s + 1) & 1]);
      projsample<<<dim3(NB), dim3(256), 0, stream>>>(
          hbuf[(s + 1) & 1], pw, pb, N_s, u + s*NB, rx + s*NB, ry + s*NB,
          u2 + s*NB, s, stroke, dout + s*NB*5);
    }
  } else {
    float* hbuf[2] = { hA, hB };
    for (int s = 0; s < 10; ++s) {
      rec_gemm_lstm<<<dim3(HID/16, NB/64), dim3(256), 0, stream>>>(
          hbuf[s & 1], W_hh, gz, W_ih, stroke, c, hbuf[(s + 1) & 1]);
      projsample<<<dim3(NB), dim3(256), 0, stream>>>(
          hbuf[(s + 1) & 1], pw, pb, N_s, u + s*NB, rx + s*NB, ry + s*NB,
          u2 + s*NB, s, stroke, dout + s*NB*5);
    }
  }
}